// Round 11
// baseline (795.393 us; speedup 1.0000x reference)
//
#include <hip/hip_runtime.h>
#include <hip/hip_bf16.h>
#include <stdint.h>

// GraphAttentionLayer kernel set for MI355X (gfx950). Round 9 (resubmit x2 —
// two consecutive GPUAcquisitionTimeouts; this source has not yet run).
// Mask experiments (R5/R8) were net losses (fused_attn is not HBM-bound);
// pipelining (R3/R8) confirmed null. This round: R2-verified structure +
// OCCUPANCY as the lever — fused_attn was grid-limited to 2 blocks/CU
// (512 blocks, LDS fits 3). j-split 2 doubles the grid; each block does
// half the K-range and writes fp32 partials + partial rowsums; a tiny
// combine kernel finishes out = (P0+P1)/(d0+d1).
// Pipeline:
//   K1 conv_wt    : W[k][c] fp32 -> WT[c][k] bf16 (LDS-tiled transpose)
//   K2 wh_gemm    : Wh = h@W + bW via bf16 MFMA -> WhT[c][i] bf16
//                   + fused s1 = Wh@a1, exp factors eb1/eb2 of s2
//   K3 fused_attn : partial PV GEMM, w computed on the fly from adj
//                   (2-phase, split-K waves, XOR-16 swizzle, factored exp)
//   K4 combine    : out = (P0+P1) * 1/(d0+d1)

#define NN 8192
#define DD 512

typedef __attribute__((ext_vector_type(8))) short short8;
typedef __attribute__((ext_vector_type(8))) unsigned short ushort8;
typedef __attribute__((ext_vector_type(4))) float f32x4;
typedef __attribute__((ext_vector_type(4))) float float4v;
typedef __attribute__((ext_vector_type(4))) unsigned short ushort4v;

__device__ __forceinline__ uint16_t f2bf(float f) {
  union { float f; uint32_t u; } v; v.f = f;
  uint32_t u = v.u;
  u += 0x7fffu + ((u >> 16) & 1u);   // round-nearest-even
  return (uint16_t)(u >> 16);
}

// packed f32 pair -> bf16x2 (RNE) via native v_cvt_pk_bf16_f32
__device__ __forceinline__ uint32_t pk2bf(float lo, float hi) {
  union { __hip_bfloat162 h; uint32_t u; } v;
  v.h = __float22bfloat162_rn(make_float2(lo, hi));
  return v.u;
}

__device__ __forceinline__ void async_copy16(uint16_t* lds, const uint16_t* g) {
  __builtin_amdgcn_global_load_lds(
      (const __attribute__((address_space(1))) uint32_t*)g,
      (__attribute__((address_space(3))) uint32_t*)lds, 16, 0, 0);
}

// ---- K1: tiled transpose+convert W (512x512) ----
__global__ __launch_bounds__(256) void conv_wt(const float* __restrict__ W,
                                               uint16_t* __restrict__ WT) {
  __shared__ float ts[64][65];
  int tid = threadIdx.x;
  int kt = (blockIdx.x >> 3) * 64, ct = (blockIdx.x & 7) * 64;
  #pragma unroll
  for (int it = 0; it < 4; ++it) {
    int idx = it * 256 + tid;
    int r = idx >> 4, q = idx & 15;
    float4v v = *(const float4v*)(W + (size_t)(kt + r) * 512 + ct + q * 4);
    ts[r][q * 4 + 0] = v.x; ts[r][q * 4 + 1] = v.y;
    ts[r][q * 4 + 2] = v.z; ts[r][q * 4 + 3] = v.w;
  }
  __syncthreads();
  #pragma unroll
  for (int it = 0; it < 4; ++it) {
    int idx = it * 256 + tid;
    int c = idx >> 4, q = idx & 15;
    ushort4v p;
    p.x = f2bf(ts[q * 4 + 0][c]); p.y = f2bf(ts[q * 4 + 1][c]);
    p.z = f2bf(ts[q * 4 + 2][c]); p.w = f2bf(ts[q * 4 + 3][c]);
    *(ushort4v*)(WT + (size_t)(ct + c) * 512 + kt + q * 4) = p;
  }
}

// ---- K2: Wh GEMM -> WhT[c][i] bf16, fused raw scores + exp factors ----
__global__ __launch_bounds__(512) void wh_gemm(const float* __restrict__ h,
                                               const uint16_t* __restrict__ WT,
                                               const float* __restrict__ bW,
                                               const float* __restrict__ a1,
                                               const float* __restrict__ a2,
                                               uint16_t* __restrict__ WhT,
                                               float* __restrict__ s1g,
                                               float* __restrict__ eb1g,
                                               float* __restrict__ eb2g) {
  __shared__ __align__(16) uint16_t At[32 * 32];
  __shared__ __align__(16) uint16_t Bt[512 * 32];
  __shared__ float s1loc[32], s2loc[32];
  int tid = threadIdx.x;
  int wave = tid >> 6, lane = tid & 63;
  int l15 = lane & 15, quad = lane >> 4;
  int i0 = blockIdx.x * 32;
  if (tid < 32) { s1loc[tid] = 0.f; s2loc[tid] = 0.f; }
  f32x4 acc[2][4] = {};
  for (int k0 = 0; k0 < 512; k0 += 32) {
    if (tid < 256) {
      int r = tid >> 3, ks = (tid & 7) * 4;
      float4v hv = *(const float4v*)(h + (size_t)(i0 + r) * 512 + k0 + ks);
      ushort4v p;
      p.x = f2bf(hv.x); p.y = f2bf(hv.y); p.z = f2bf(hv.z); p.w = f2bf(hv.w);
      *(ushort4v*)&At[r * 32 + ks] = p;
    }
    #pragma unroll
    for (int rr = 0; rr < 4; ++rr) {
      int idx = rr * 512 + tid;
      int c = idx >> 2, q = idx & 3;
      async_copy16(&Bt[idx * 8], WT + c * 512 + k0 + q * 8);
    }
    __syncthreads();
    short8 a0 = *(const short8*)&At[l15 * 32 + quad * 8];
    short8 a1f = *(const short8*)&At[(l15 + 16) * 32 + quad * 8];
    #pragma unroll
    for (int nt = 0; nt < 4; ++nt) {
      int c = wave * 64 + nt * 16 + l15;
      short8 b = *(const short8*)&Bt[c * 32 + quad * 8];
      acc[0][nt] = __builtin_amdgcn_mfma_f32_16x16x32_bf16(a0, b, acc[0][nt], 0, 0, 0);
      acc[1][nt] = __builtin_amdgcn_mfma_f32_16x16x32_bf16(a1f, b, acc[1][nt], 0, 0, 0);
    }
    __syncthreads();
  }
  // epilogue: bias, write WhT, per-row score partials
  #pragma unroll
  for (int mt = 0; mt < 2; ++mt) {
    int ib = i0 + mt * 16 + quad * 4;
    float r1[4] = {0.f, 0.f, 0.f, 0.f};
    float r2[4] = {0.f, 0.f, 0.f, 0.f};
    #pragma unroll
    for (int nt = 0; nt < 4; ++nt) {
      int c = wave * 64 + nt * 16 + l15;
      float bias = bW[c];
      float a1c = a1[c], a2c = a2[c];
      float v0 = acc[mt][nt].x + bias;
      float v1 = acc[mt][nt].y + bias;
      float v2 = acc[mt][nt].z + bias;
      float v3 = acc[mt][nt].w + bias;
      ushort4v p;
      p.x = f2bf(v0); p.y = f2bf(v1); p.z = f2bf(v2); p.w = f2bf(v3);
      *(ushort4v*)&WhT[(size_t)c * 8192 + ib] = p;
      r1[0] = fmaf(v0, a1c, r1[0]); r1[1] = fmaf(v1, a1c, r1[1]);
      r1[2] = fmaf(v2, a1c, r1[2]); r1[3] = fmaf(v3, a1c, r1[3]);
      r2[0] = fmaf(v0, a2c, r2[0]); r2[1] = fmaf(v1, a2c, r2[1]);
      r2[2] = fmaf(v2, a2c, r2[2]); r2[3] = fmaf(v3, a2c, r2[3]);
    }
    #pragma unroll
    for (int v = 0; v < 4; ++v) {
      int row = mt * 16 + quad * 4 + v;
      atomicAdd(&s1loc[row], r1[v]);
      atomicAdd(&s2loc[row], r2[v]);
    }
  }
  __syncthreads();
  if (tid < 32) {
    s1g[i0 + tid] = s1loc[tid];
    float v2 = s2loc[tid];
    eb1g[i0 + tid] = __expf(v2);
    eb2g[i0 + tid] = __expf(0.2f * v2);
  }
}

// score: w = adj>0 ? max(A1*eb1_j, A2*eb2_j) : 0   (== adj?exp(lrelu(t)):0)
#define SCORE(aval, e1, e2, A1v, A2v, rs, dst)                       \
  { float m_ = fmaxf((A1v) * (e1), (A2v) * (e2));                    \
    m_ = ((aval) > 0) ? m_ : 0.f;                                    \
    (rs) += m_; (dst) = m_; }

// ---- K3: fused attention partial: Pp[js] = w @ WhT^T over the js j-half,
// w computed on the fly. 64x128 tile, BK=128, 512 thr = (rg2 x cg2 x kg2
// split-K). R2-verified 2-phase inner loop. Grid (SPLIT): 1024 blocks =
// rb 128 x cb 4 x js 2 -> 3 blocks/CU resident (LDS 49.4 KB). Block map:
// the cb/js sharers of an adj row-stripe are 128/512 apart == same XCD.
template<bool SPLIT>
__global__ __launch_bounds__(512, 6) void fused_attn(const int* __restrict__ adj,
                                                     const float* __restrict__ s1,
                                                     const float* __restrict__ b1,
                                                     const float* __restrict__ b2,
                                                     const float* __restrict__ eb1,
                                                     const float* __restrict__ eb2,
                                                     const uint16_t* __restrict__ WhT,
                                                     float* __restrict__ Pp,
                                                     float* __restrict__ dpart,
                                                     float* __restrict__ out) {
  __shared__ __align__(16) uint16_t At[64 * 128];    // 16 KB, XOR-16 swizzled
  __shared__ __align__(16) uint16_t Bt[128 * 128];   // 32 KB, XOR-16 swizzled
  __shared__ float sdv[64];
  int tid = threadIdx.x;
  int wave = tid >> 6, lane = tid & 63;
  int l15 = lane & 15, quad = lane >> 4;
  int kg = wave & 1, rg = (wave >> 1) & 1, cg = wave >> 2;
  int bid = blockIdx.x;
  int rb = bid & 127, cb = (bid >> 7) & 3;
  int js = SPLIT ? (bid >> 9) : 0;
  int i0 = rb * 64, c0 = cb * 128;
  int jbase = js * 4096;
  int niter = SPLIT ? 32 : 64;
  int r0 = tid >> 4, pp = tid & 15;           // r0 in [0,32), chunk slot pp
  int sc = pp ^ (r0 & 15);                    // source chunk (involution)
  const int* arow0 = adj + (size_t)(i0 + r0) * NN + sc * 8;
  const int* arow1 = arow0 + (size_t)32 * NN;
  float bias = b1[0] + b2[0];
  float base0 = s1[i0 + r0] + bias;
  float base1 = s1[i0 + r0 + 32] + bias;
  float A10 = __expf(base0), A20 = __expf(0.2f * base0);
  float A11 = __expf(base1), A21 = __expf(0.2f * base1);
  float rsum0 = 0.f, rsum1 = 0.f;
  uint16_t* at0 = &At[(r0 * 16 + pp) * 8];
  uint16_t* at1 = &At[((r0 + 32) * 16 + pp) * 8];
  f32x4 acc[2][4] = {};
  for (int it = 0; it < niter; ++it) {
    int j0 = jbase + it * 128;
    // A-side inputs first (oldest in vmcnt queue)
    int4 a00 = *(const int4*)(arow0 + j0);
    int4 a01 = *(const int4*)(arow0 + j0 + 4);
    int4 a10 = *(const int4*)(arow1 + j0);
    int4 a11 = *(const int4*)(arow1 + j0 + 4);
    float4v e1v0 = *(const float4v*)(eb1 + j0 + sc * 8);
    float4v e1v1 = *(const float4v*)(eb1 + j0 + sc * 8 + 4);
    float4v e2v0 = *(const float4v*)(eb2 + j0 + sc * 8);
    float4v e2v1 = *(const float4v*)(eb2 + j0 + sc * 8 + 4);
    // B: 128 rows x 128 j = 32 KB = 2048 x 16B chunks, 4/thread (async DMA)
    #pragma unroll
    for (int bi = 0; bi < 4; ++bi) {
      int idx = bi * 512 + tid;
      int r = idx >> 4, q = idx & 15;
      int bsc = q ^ (r & 15);
      async_copy16(&Bt[idx * 8], WhT + (size_t)(c0 + r) * NN + j0 + bsc * 8);
    }
    // scores: no transcendentals (factored exp), pack via cvt_pk
    float t0[8], t1[8];
    SCORE(a00.x, e1v0.x, e2v0.x, A10, A20, rsum0, t0[0]);
    SCORE(a00.y, e1v0.y, e2v0.y, A10, A20, rsum0, t0[1]);
    SCORE(a00.z, e1v0.z, e2v0.z, A10, A20, rsum0, t0[2]);
    SCORE(a00.w, e1v0.w, e2v0.w, A10, A20, rsum0, t0[3]);
    SCORE(a01.x, e1v1.x, e2v1.x, A10, A20, rsum0, t0[4]);
    SCORE(a01.y, e1v1.y, e2v1.y, A10, A20, rsum0, t0[5]);
    SCORE(a01.z, e1v1.z, e2v1.z, A10, A20, rsum0, t0[6]);
    SCORE(a01.w, e1v1.w, e2v1.w, A10, A20, rsum0, t0[7]);
    SCORE(a10.x, e1v0.x, e2v0.x, A11, A21, rsum1, t1[0]);
    SCORE(a10.y, e1v0.y, e2v0.y, A11, A21, rsum1, t1[1]);
    SCORE(a10.z, e1v0.z, e2v0.z, A11, A21, rsum1, t1[2]);
    SCORE(a10.w, e1v0.w, e2v0.w, A11, A21, rsum1, t1[3]);
    SCORE(a11.x, e1v1.x, e2v1.x, A11, A21, rsum1, t1[4]);
    SCORE(a11.y, e1v1.y, e2v1.y, A11, A21, rsum1, t1[5]);
    SCORE(a11.z, e1v1.z, e2v1.z, A11, A21, rsum1, t1[6]);
    SCORE(a11.w, e1v1.w, e2v1.w, A11, A21, rsum1, t1[7]);
    ushort8 w0, w1;
    uint32_t* pw0 = (uint32_t*)&w0;
    uint32_t* pw1 = (uint32_t*)&w1;
    pw0[0] = pk2bf(t0[0], t0[1]); pw0[1] = pk2bf(t0[2], t0[3]);
    pw0[2] = pk2bf(t0[4], t0[5]); pw0[3] = pk2bf(t0[6], t0[7]);
    pw1[0] = pk2bf(t1[0], t1[1]); pw1[1] = pk2bf(t1[2], t1[3]);
    pw1[2] = pk2bf(t1[4], t1[5]); pw1[3] = pk2bf(t1[6], t1[7]);
    *(ushort8*)at0 = w0;
    *(ushort8*)at1 = w1;
    __syncthreads();
    // MFMA phase: split-K — wave covers k in [kg*64, kg*64+64)
    #pragma unroll
    for (int kc = 0; kc < 2; ++kc) {
      int ch = kg * 8 + kc * 4 + quad;
      int ar0 = rg * 32 + l15, ar1 = ar0 + 16;
      short8 a0 = *(const short8*)&At[ar0 * 128 + ((ch ^ (ar0 & 15)) * 8)];
      short8 a1f = *(const short8*)&At[ar1 * 128 + ((ch ^ (ar1 & 15)) * 8)];
      #pragma unroll
      for (int ct = 0; ct < 4; ++ct) {
        int br = cg * 64 + ct * 16 + l15;
        short8 b = *(const short8*)&Bt[br * 128 + ((ch ^ (br & 15)) * 8)];
        acc[0][ct] = __builtin_amdgcn_mfma_f32_16x16x32_bf16(a0, b, acc[0][ct], 0, 0, 0);
        acc[1][ct] = __builtin_amdgcn_mfma_f32_16x16x32_bf16(a1f, b, acc[1][ct], 0, 0, 0);
      }
    }
    __syncthreads();
  }
  // rowsum: reduce the 16 chunk-partials of each row (16 consecutive lanes)
  #pragma unroll
  for (int o = 1; o < 16; o <<= 1) {
    rsum0 += __shfl_xor(rsum0, o);
    rsum1 += __shfl_xor(rsum1, o);
  }
  if (SPLIT) {
    if (pp == 0 && cb == 0) {
      dpart[js * NN + i0 + r0] = rsum0;
      dpart[js * NN + i0 + r0 + 32] = rsum1;
    }
  } else {
    if (pp == 0) {
      sdv[r0] = 1.0f / rsum0;
      sdv[r0 + 32] = 1.0f / rsum1;
    }
  }
  // split-K reduction: kg=1 waves dump acc into Bt, kg=0 add (+scale) +store
  float* red = (float*)Bt;
  int pid = rg * 2 + cg;
  __syncthreads();
  if (kg == 1) {
    #pragma unroll
    for (int rt = 0; rt < 2; ++rt)
      #pragma unroll
      for (int ct = 0; ct < 4; ++ct)
        #pragma unroll
        for (int v = 0; v < 4; ++v)
          red[pid * 2048 + ((rt * 4 + ct) * 4 + v) * 64 + lane] = acc[rt][ct][v];
  }
  __syncthreads();
  if (kg == 0) {
    #pragma unroll
    for (int rt = 0; rt < 2; ++rt) {
      #pragma unroll
      for (int v = 0; v < 4; ++v) {
        int rloc = rg * 32 + rt * 16 + quad * 4 + v;
        float dv = SPLIT ? 1.0f : sdv[rloc];
        #pragma unroll
        for (int ct = 0; ct < 4; ++ct) {
          float s = acc[rt][ct][v] + red[pid * 2048 + ((rt * 4 + ct) * 4 + v) * 64 + lane];
          size_t o = (size_t)(i0 + rloc) * DD + c0 + cg * 64 + ct * 16 + l15;
          if (SPLIT) Pp[(size_t)js * NN * DD + o] = s;
          else out[o] = s * dv;
        }
      }
    }
  }
}

// ---- K4: out = (P0+P1) * 1/(d0+d1). 4096 blocks x 256 thr, 1 float4/thr.
__global__ __launch_bounds__(256) void combine(const float* __restrict__ Pp,
                                               const float* __restrict__ dpart,
                                               float* __restrict__ out) {
  int idx = blockIdx.x * 256 + threadIdx.x;   // float4 index
  int i = idx >> 7;                           // row (128 float4 per row)
  float4v p0 = *(const float4v*)(Pp + (size_t)idx * 4);
  float4v p1 = *(const float4v*)(Pp + (size_t)NN * DD + (size_t)idx * 4);
  float dv = 1.0f / (dpart[i] + dpart[NN + i]);
  float4v o;
  o.x = (p0.x + p1.x) * dv;
  o.y = (p0.y + p1.y) * dv;
  o.z = (p0.z + p1.z) * dv;
  o.w = (p0.w + p1.w) * dv;
  *(float4v*)(out + (size_t)idx * 4) = o;
}

extern "C" void kernel_launch(void* const* d_in, const int* in_sizes, int n_in,
                              void* d_out, int out_size, void* d_ws, size_t ws_size,
                              hipStream_t stream) {
  const float* h   = (const float*)d_in[0];
  const int*   adj = (const int*)d_in[1];
  const float* W   = (const float*)d_in[2];
  const float* bW  = (const float*)d_in[3];
  const float* a1  = (const float*)d_in[4];
  const float* b1  = (const float*)d_in[5];
  const float* a2  = (const float*)d_in[6];
  const float* b2  = (const float*)d_in[7];
  float* out = (float*)d_out;
  char* ws = (char*)d_ws;

  uint16_t* WhT = (uint16_t*)(ws);                 // 8388608
  uint16_t* WT  = (uint16_t*)(ws + 8388608);       // 524288
  float* s1     = (float*)(ws + 8912896);          // 32768
  float* eb1    = (float*)(ws + 8945664);          // 32768
  float* eb2    = (float*)(ws + 8978432);          // 32768
  float* Pp     = (float*)(ws + 9011200);          // 33554432 (2x 16 MB)
  float* dpart  = (float*)(ws + 42565632);         // 65536
  const size_t NEED = 42631168ULL;

  conv_wt<<<64, 256, 0, stream>>>(W, WT);
  wh_gemm<<<256, 512, 0, stream>>>(h, WT, bW, a1, a2, WhT, s1, eb1, eb2);
  if (ws_size >= NEED) {
    fused_attn<true><<<1024, 512, 0, stream>>>(adj, s1, b1, b2, eb1, eb2,
                                               WhT, Pp, dpart, out);
    combine<<<4096, 256, 0, stream>>>(Pp, dpart, out);
  } else {
    fused_attn<false><<<512, 512, 0, stream>>>(adj, s1, b1, b2, eb1, eb2,
                                               WhT, Pp, dpart, out);
  }
}

// Round 12
// 644.928 us; speedup vs baseline: 1.2333x; 1.2333x over previous
//
#include <hip/hip_runtime.h>
#include <hip/hip_bf16.h>
#include <stdint.h>

// GraphAttentionLayer kernel set for MI355X (gfx950). Round 12.
// Verdicts so far: mask compression (R5/R8) NEGATIVE; B-side pipelining
// (R3/R8) NULL-to-NEGATIVE; occupancy j-split (R11) VERY NEGATIVE (L3
// adj-sharing collapsed: FETCH 210->613 MB). R2's 2-phase single-buffer
// structure (196 us, FETCH 210 MB) is the measured optimum; its cost is
// the per-iter serial chain led by the adj load latency (~900 cy waited
// immediately by the score phase).
// This round: A-SIDE REGISTER PREFETCH ONLY — adj+eb for iter t+1 loaded
// into an alternate register set at the top of iter t (unroll-2, static
// sets). Scores read registers loaded a full iteration earlier; the
// prefetch drains at the barrier that already waits for the B-DMA.
// Nothing else changes: same grid (512), same LDS (49.6 KB, 2 blocks/CU),
// same single-buffer Bt, same split-K waves, same XOR-16 swizzle.
// Pipeline:
//   K1 conv_wt    : W[k][c] fp32 -> WT[c][k] bf16 (LDS-tiled transpose)
//   K2 wh_gemm    : Wh = h@W + bW via bf16 MFMA -> WhT[c][i] bf16
//                   + fused s1 = Wh@a1, exp factors eb1/eb2 of s2
//   K3 fused_attn : out = softmax_row(mask(lrelu(s1_i+s2_j))) @ Wh,
//                   w on the fly, A-side prefetched.

#define NN 8192
#define DD 512

typedef __attribute__((ext_vector_type(8))) short short8;
typedef __attribute__((ext_vector_type(8))) unsigned short ushort8;
typedef __attribute__((ext_vector_type(4))) float f32x4;
typedef __attribute__((ext_vector_type(4))) float float4v;
typedef __attribute__((ext_vector_type(4))) unsigned short ushort4v;

__device__ __forceinline__ uint16_t f2bf(float f) {
  union { float f; uint32_t u; } v; v.f = f;
  uint32_t u = v.u;
  u += 0x7fffu + ((u >> 16) & 1u);   // round-nearest-even
  return (uint16_t)(u >> 16);
}

// packed f32 pair -> bf16x2 (RNE) via native v_cvt_pk_bf16_f32
__device__ __forceinline__ uint32_t pk2bf(float lo, float hi) {
  union { __hip_bfloat162 h; uint32_t u; } v;
  v.h = __float22bfloat162_rn(make_float2(lo, hi));
  return v.u;
}

__device__ __forceinline__ void async_copy16(uint16_t* lds, const uint16_t* g) {
  __builtin_amdgcn_global_load_lds(
      (const __attribute__((address_space(1))) uint32_t*)g,
      (__attribute__((address_space(3))) uint32_t*)lds, 16, 0, 0);
}

// ---- K1: tiled transpose+convert W (512x512) ----
__global__ __launch_bounds__(256) void conv_wt(const float* __restrict__ W,
                                               uint16_t* __restrict__ WT) {
  __shared__ float ts[64][65];
  int tid = threadIdx.x;
  int kt = (blockIdx.x >> 3) * 64, ct = (blockIdx.x & 7) * 64;
  #pragma unroll
  for (int it = 0; it < 4; ++it) {
    int idx = it * 256 + tid;
    int r = idx >> 4, q = idx & 15;
    float4v v = *(const float4v*)(W + (size_t)(kt + r) * 512 + ct + q * 4);
    ts[r][q * 4 + 0] = v.x; ts[r][q * 4 + 1] = v.y;
    ts[r][q * 4 + 2] = v.z; ts[r][q * 4 + 3] = v.w;
  }
  __syncthreads();
  #pragma unroll
  for (int it = 0; it < 4; ++it) {
    int idx = it * 256 + tid;
    int c = idx >> 4, q = idx & 15;
    ushort4v p;
    p.x = f2bf(ts[q * 4 + 0][c]); p.y = f2bf(ts[q * 4 + 1][c]);
    p.z = f2bf(ts[q * 4 + 2][c]); p.w = f2bf(ts[q * 4 + 3][c]);
    *(ushort4v*)(WT + (size_t)(ct + c) * 512 + kt + q * 4) = p;
  }
}

// ---- K2: Wh GEMM -> WhT[c][i] bf16, fused raw scores + exp factors ----
__global__ __launch_bounds__(512) void wh_gemm(const float* __restrict__ h,
                                               const uint16_t* __restrict__ WT,
                                               const float* __restrict__ bW,
                                               const float* __restrict__ a1,
                                               const float* __restrict__ a2,
                                               uint16_t* __restrict__ WhT,
                                               float* __restrict__ s1g,
                                               float* __restrict__ eb1g,
                                               float* __restrict__ eb2g) {
  __shared__ __align__(16) uint16_t At[32 * 32];
  __shared__ __align__(16) uint16_t Bt[512 * 32];
  __shared__ float s1loc[32], s2loc[32];
  int tid = threadIdx.x;
  int wave = tid >> 6, lane = tid & 63;
  int l15 = lane & 15, quad = lane >> 4;
  int i0 = blockIdx.x * 32;
  if (tid < 32) { s1loc[tid] = 0.f; s2loc[tid] = 0.f; }
  f32x4 acc[2][4] = {};
  for (int k0 = 0; k0 < 512; k0 += 32) {
    if (tid < 256) {
      int r = tid >> 3, ks = (tid & 7) * 4;
      float4v hv = *(const float4v*)(h + (size_t)(i0 + r) * 512 + k0 + ks);
      ushort4v p;
      p.x = f2bf(hv.x); p.y = f2bf(hv.y); p.z = f2bf(hv.z); p.w = f2bf(hv.w);
      *(ushort4v*)&At[r * 32 + ks] = p;
    }
    #pragma unroll
    for (int rr = 0; rr < 4; ++rr) {
      int idx = rr * 512 + tid;
      int c = idx >> 2, q = idx & 3;
      async_copy16(&Bt[idx * 8], WT + c * 512 + k0 + q * 8);
    }
    __syncthreads();
    short8 a0 = *(const short8*)&At[l15 * 32 + quad * 8];
    short8 a1f = *(const short8*)&At[(l15 + 16) * 32 + quad * 8];
    #pragma unroll
    for (int nt = 0; nt < 4; ++nt) {
      int c = wave * 64 + nt * 16 + l15;
      short8 b = *(const short8*)&Bt[c * 32 + quad * 8];
      acc[0][nt] = __builtin_amdgcn_mfma_f32_16x16x32_bf16(a0, b, acc[0][nt], 0, 0, 0);
      acc[1][nt] = __builtin_amdgcn_mfma_f32_16x16x32_bf16(a1f, b, acc[1][nt], 0, 0, 0);
    }
    __syncthreads();
  }
  // epilogue: bias, write WhT, per-row score partials
  #pragma unroll
  for (int mt = 0; mt < 2; ++mt) {
    int ib = i0 + mt * 16 + quad * 4;
    float r1[4] = {0.f, 0.f, 0.f, 0.f};
    float r2[4] = {0.f, 0.f, 0.f, 0.f};
    #pragma unroll
    for (int nt = 0; nt < 4; ++nt) {
      int c = wave * 64 + nt * 16 + l15;
      float bias = bW[c];
      float a1c = a1[c], a2c = a2[c];
      float v0 = acc[mt][nt].x + bias;
      float v1 = acc[mt][nt].y + bias;
      float v2 = acc[mt][nt].z + bias;
      float v3 = acc[mt][nt].w + bias;
      ushort4v p;
      p.x = f2bf(v0); p.y = f2bf(v1); p.z = f2bf(v2); p.w = f2bf(v3);
      *(ushort4v*)&WhT[(size_t)c * 8192 + ib] = p;
      r1[0] = fmaf(v0, a1c, r1[0]); r1[1] = fmaf(v1, a1c, r1[1]);
      r1[2] = fmaf(v2, a1c, r1[2]); r1[3] = fmaf(v3, a1c, r1[3]);
      r2[0] = fmaf(v0, a2c, r2[0]); r2[1] = fmaf(v1, a2c, r2[1]);
      r2[2] = fmaf(v2, a2c, r2[2]); r2[3] = fmaf(v3, a2c, r2[3]);
    }
    #pragma unroll
    for (int v = 0; v < 4; ++v) {
      int row = mt * 16 + quad * 4 + v;
      atomicAdd(&s1loc[row], r1[v]);
      atomicAdd(&s2loc[row], r2[v]);
    }
  }
  __syncthreads();
  if (tid < 32) {
    s1g[i0 + tid] = s1loc[tid];
    float v2 = s2loc[tid];
    eb1g[i0 + tid] = __expf(v2);
    eb2g[i0 + tid] = __expf(0.2f * v2);
  }
}

// ---- fused_attn helper macros (token-pasted register sets) ----
#define DECLA(S) int4 a00##S, a01##S, a10##S, a11##S;                \
                 float4v e1v0##S, e1v1##S, e2v0##S, e2v1##S;

#define LOADA(S, j0_)                                                \
  a00##S = *(const int4*)(arow0 + (j0_));                            \
  a01##S = *(const int4*)(arow0 + (j0_) + 4);                        \
  a10##S = *(const int4*)(arow1 + (j0_));                            \
  a11##S = *(const int4*)(arow1 + (j0_) + 4);                        \
  e1v0##S = *(const float4v*)(eb1 + (j0_) + sc * 8);                 \
  e1v1##S = *(const float4v*)(eb1 + (j0_) + sc * 8 + 4);             \
  e2v0##S = *(const float4v*)(eb2 + (j0_) + sc * 8);                 \
  e2v1##S = *(const float4v*)(eb2 + (j0_) + sc * 8 + 4);

// pair-score + pack (keeps only 2 floats live per pair)
#define SCPK(pw, idx, aF0, eF0, gF0, aF1, eF1, gF1, A1v, A2v, rs)    \
  { float x_ = fmaxf((A1v) * (eF0), (A2v) * (gF0));                  \
    x_ = ((aF0) > 0) ? x_ : 0.f; (rs) += x_;                         \
    float y_ = fmaxf((A1v) * (eF1), (A2v) * (gF1));                  \
    y_ = ((aF1) > 0) ? y_ : 0.f; (rs) += y_;                         \
    (pw)[idx] = pk2bf(x_, y_); }

#define SCOREPACK(S)                                                 \
  { uint32_t* pw0 = (uint32_t*)&w0;                                  \
    uint32_t* pw1 = (uint32_t*)&w1;                                  \
    SCPK(pw0, 0, a00##S.x, e1v0##S.x, e2v0##S.x,                     \
                 a00##S.y, e1v0##S.y, e2v0##S.y, A10, A20, rsum0);   \
    SCPK(pw0, 1, a00##S.z, e1v0##S.z, e2v0##S.z,                     \
                 a00##S.w, e1v0##S.w, e2v0##S.w, A10, A20, rsum0);   \
    SCPK(pw0, 2, a01##S.x, e1v1##S.x, e2v1##S.x,                     \
                 a01##S.y, e1v1##S.y, e2v1##S.y, A10, A20, rsum0);   \
    SCPK(pw0, 3, a01##S.z, e1v1##S.z, e2v1##S.z,                     \
                 a01##S.w, e1v1##S.w, e2v1##S.w, A10, A20, rsum0);   \
    SCPK(pw1, 0, a10##S.x, e1v0##S.x, e2v0##S.x,                     \
                 a10##S.y, e1v0##S.y, e2v0##S.y, A11, A21, rsum1);   \
    SCPK(pw1, 1, a10##S.z, e1v0##S.z, e2v0##S.z,                     \
                 a10##S.w, e1v0##S.w, e2v0##S.w, A11, A21, rsum1);   \
    SCPK(pw1, 2, a11##S.x, e1v1##S.x, e2v1##S.x,                     \
                 a11##S.y, e1v1##S.y, e2v1##S.y, A11, A21, rsum1);   \
    SCPK(pw1, 3, a11##S.z, e1v1##S.z, e2v1##S.z,                     \
                 a11##S.w, e1v1##S.w, e2v1##S.w, A11, A21, rsum1); }

#define BDMA(j0_)                                                    \
  _Pragma("unroll")                                                  \
  for (int bi = 0; bi < 4; ++bi) {                                   \
    int idx = bi * 512 + tid;                                        \
    int r = idx >> 4, q = idx & 15;                                  \
    int bsc = q ^ (r & 15);                                          \
    async_copy16(&Bt[idx * 8], WhT + (size_t)(c0 + r) * NN + (j0_) + bsc * 8); \
  }

#define MFMAPHASE()                                                  \
  _Pragma("unroll")                                                  \
  for (int kc = 0; kc < 2; ++kc) {                                   \
    int ch = kg * 8 + kc * 4 + quad;                                 \
    int ar0 = rg * 32 + l15, ar1 = ar0 + 16;                         \
    short8 a0 = *(const short8*)&At[ar0 * 128 + ((ch ^ (ar0 & 15)) * 8)];  \
    short8 a1f = *(const short8*)&At[ar1 * 128 + ((ch ^ (ar1 & 15)) * 8)]; \
    _Pragma("unroll")                                                \
    for (int ct = 0; ct < 4; ++ct) {                                 \
      int br = cg * 64 + ct * 16 + l15;                              \
      short8 b = *(const short8*)&Bt[br * 128 + ((ch ^ (br & 15)) * 8)];   \
      acc[0][ct] = __builtin_amdgcn_mfma_f32_16x16x32_bf16(a0, b, acc[0][ct], 0, 0, 0);  \
      acc[1][ct] = __builtin_amdgcn_mfma_f32_16x16x32_bf16(a1f, b, acc[1][ct], 0, 0, 0); \
    }                                                                \
  }

// ---- K3: fused attention: out = (w @ WhT^T) * dinv, w on the fly.
// R2-verified 2-phase loop + A-side register prefetch (unroll-2, alternate
// sets). 64x128 tile, BK=128, 512 thr = (rg2 x cg2 x kg2 split-K).
// Block map: rb = blockIdx&127, cb = blockIdx>>7 -> 4 blocks sharing an
// adj row-stripe are 128 apart == same XCD.
__global__ __launch_bounds__(512, 4) void fused_attn(const int* __restrict__ adj,
                                                     const float* __restrict__ s1,
                                                     const float* __restrict__ b1,
                                                     const float* __restrict__ b2,
                                                     const float* __restrict__ eb1,
                                                     const float* __restrict__ eb2,
                                                     const uint16_t* __restrict__ WhT,
                                                     float* __restrict__ out) {
  __shared__ __align__(16) uint16_t At[64 * 128];    // 16 KB, XOR-16 swizzled
  __shared__ __align__(16) uint16_t Bt[128 * 128];   // 32 KB, XOR-16 swizzled
  __shared__ float sdv[64];
  int tid = threadIdx.x;
  int wave = tid >> 6, lane = tid & 63;
  int l15 = lane & 15, quad = lane >> 4;
  int kg = wave & 1, rg = (wave >> 1) & 1, cg = wave >> 2;
  int rb = blockIdx.x & 127, cb = blockIdx.x >> 7;
  int i0 = rb * 64, c0 = cb * 128;
  int r0 = tid >> 4, pp = tid & 15;           // r0 in [0,32), chunk slot pp
  int sc = pp ^ (r0 & 15);                    // source chunk (involution)
  const int* arow0 = adj + (size_t)(i0 + r0) * NN + sc * 8;
  const int* arow1 = arow0 + (size_t)32 * NN;
  float bias = b1[0] + b2[0];
  float base0 = s1[i0 + r0] + bias;
  float base1 = s1[i0 + r0 + 32] + bias;
  float A10 = __expf(base0), A20 = __expf(0.2f * base0);
  float A11 = __expf(base1), A21 = __expf(0.2f * base1);
  float rsum0 = 0.f, rsum1 = 0.f;
  uint16_t* at0 = &At[(r0 * 16 + pp) * 8];
  uint16_t* at1 = &At[((r0 + 32) * 16 + pp) * 8];
  f32x4 acc[2][4] = {};
  DECLA(A) DECLA(B)
  ushort8 w0, w1;

  LOADA(A, 0);                      // prologue: A-side of tile 0
  for (int tt = 0; tt < 32; ++tt) {
    int ja = tt * 256;              // = (2*tt) * 128
    // ---- iter 2tt (set A); prefetch set B for iter 2tt+1 ----
    LOADA(B, ja + 128);             // issued early, used next half-iter
    BDMA(ja);
    SCOREPACK(A);                   // waits set-A loads (a full iter old)
    *(ushort8*)at0 = w0;
    *(ushort8*)at1 = w1;
    __syncthreads();                // At visible; B-DMA + prefetch drained
    MFMAPHASE();
    __syncthreads();
    // ---- iter 2tt+1 (set B); prefetch set A for iter 2tt+2 ----
    if (tt < 31) { LOADA(A, ja + 256); }
    BDMA(ja + 128);
    SCOREPACK(B);
    *(ushort8*)at0 = w0;
    *(ushort8*)at1 = w1;
    __syncthreads();
    MFMAPHASE();
    __syncthreads();
  }

  // dinv: reduce the 16 chunk-partials of each row (16 consecutive lanes)
  #pragma unroll
  for (int o = 1; o < 16; o <<= 1) {
    rsum0 += __shfl_xor(rsum0, o);
    rsum1 += __shfl_xor(rsum1, o);
  }
  if (pp == 0) {
    sdv[r0] = 1.0f / rsum0;
    sdv[r0 + 32] = 1.0f / rsum1;
  }
  // split-K reduction: kg=1 waves dump acc into Bt, kg=0 add + scale + store
  float* red = (float*)Bt;
  int pid = rg * 2 + cg;
  __syncthreads();
  if (kg == 1) {
    #pragma unroll
    for (int rt = 0; rt < 2; ++rt)
      #pragma unroll
      for (int ct = 0; ct < 4; ++ct)
        #pragma unroll
        for (int v = 0; v < 4; ++v)
          red[pid * 2048 + ((rt * 4 + ct) * 4 + v) * 64 + lane] = acc[rt][ct][v];
  }
  __syncthreads();
  if (kg == 0) {
    #pragma unroll
    for (int rt = 0; rt < 2; ++rt) {
      #pragma unroll
      for (int v = 0; v < 4; ++v) {
        int rloc = rg * 32 + rt * 16 + quad * 4 + v;
        float dv = sdv[rloc];
        #pragma unroll
        for (int ct = 0; ct < 4; ++ct) {
          float s = acc[rt][ct][v] + red[pid * 2048 + ((rt * 4 + ct) * 4 + v) * 64 + lane];
          out[(size_t)(i0 + rloc) * DD + c0 + cg * 64 + ct * 16 + l15] = s * dv;
        }
      }
    }
  }
}

extern "C" void kernel_launch(void* const* d_in, const int* in_sizes, int n_in,
                              void* d_out, int out_size, void* d_ws, size_t ws_size,
                              hipStream_t stream) {
  const float* h   = (const float*)d_in[0];
  const int*   adj = (const int*)d_in[1];
  const float* W   = (const float*)d_in[2];
  const float* bW  = (const float*)d_in[3];
  const float* a1  = (const float*)d_in[4];
  const float* b1  = (const float*)d_in[5];
  const float* a2  = (const float*)d_in[6];
  const float* b2  = (const float*)d_in[7];
  float* out = (float*)d_out;
  char* ws = (char*)d_ws;

  uint16_t* WhT = (uint16_t*)(ws);                 // 8388608
  uint16_t* WT  = (uint16_t*)(ws + 8388608);       // 524288
  float* s1     = (float*)(ws + 8912896);          // 32768
  float* eb1    = (float*)(ws + 8945664);          // 32768
  float* eb2    = (float*)(ws + 8978432);          // 32768

  conv_wt<<<64, 256, 0, stream>>>(W, WT);
  wh_gemm<<<256, 512, 0, stream>>>(h, WT, bW, a1, a2, WhT, s1, eb1, eb2);
  fused_attn<<<512, 512, 0, stream>>>(adj, s1, b1, b2, eb1, eb2, WhT, out);
}

// Round 13
// 499.070 us; speedup vs baseline: 1.5938x; 1.2923x over previous
//
#include <hip/hip_runtime.h>
#include <hip/hip_bf16.h>
#include <stdint.h>

// GraphAttentionLayer kernel set for MI355X (gfx950). Round 13 — REVERT to
// the measured session optimum (R2 source, 500.47 us total; fused_attn
// 196 us, FETCH 210 MB). Six mutations all regressed: B-side pipelining
// (R3/R8), bitmask compression (R5/R8), occupancy j-split (R11, FETCH
// 210->613 MB), A-side register prefetch (R12, scratch spills WRITE
// 16->167 MB + L3 adj-reuse collapse). The adj stream (256 MB ~= L3
// capacity) makes the 4-block XCD reuse equilibrium fragile: any timing
// or pressure perturbation re-streams adj from HBM and loses more than
// the overlap gains.
// Pipeline (3 kernels — w never materialized):
//   K1 conv_wt    : W[k][c] fp32 -> WT[c][k] bf16 (LDS-tiled transpose)
//   K2 wh_gemm    : Wh = h@W + bW via bf16 MFMA -> WhT[c][i] bf16
//                   + fused raw scores s1 = Wh@a1 (+epilogue exp factors
//                   eb1 = exp(s2_j), eb2 = exp(0.2*s2_j))
//   K3 fused_attn : out = softmax_row(mask(lrelu(s1_i+s2_j))) @ Wh.
//      * score math factored: exp(lrelu(t)) == max(exp(t), exp(0.2t)),
//        exp(t) = exp(base_i)*eb1[j] -> inner loop is mul+max+cndmask,
//        NO transcendental; bf16 pack via native v_cvt_pk_bf16_f32.
//      * split-K wave mapping (2 rg x 2 cg x 2 kg): A-tile LDS reads
//        drop from 8x-redundant to 96 KB/blk-iter; one cross-wave acc
//        reduction through LDS at the end.
//   Tile 64x128, BK=128, 512 thr, XOR-16 LDS swizzle, XCD-aware block map.

#define NN 8192
#define DD 512

typedef __attribute__((ext_vector_type(8))) short short8;
typedef __attribute__((ext_vector_type(8))) unsigned short ushort8;
typedef __attribute__((ext_vector_type(4))) float f32x4;
typedef __attribute__((ext_vector_type(4))) float float4v;
typedef __attribute__((ext_vector_type(4))) unsigned short ushort4v;

__device__ __forceinline__ uint16_t f2bf(float f) {
  union { float f; uint32_t u; } v; v.f = f;
  uint32_t u = v.u;
  u += 0x7fffu + ((u >> 16) & 1u);   // round-nearest-even
  return (uint16_t)(u >> 16);
}

// packed f32 pair -> bf16x2 (RNE) via native v_cvt_pk_bf16_f32
__device__ __forceinline__ uint32_t pk2bf(float lo, float hi) {
  union { __hip_bfloat162 h; uint32_t u; } v;
  v.h = __float22bfloat162_rn(make_float2(lo, hi));
  return v.u;
}

__device__ __forceinline__ void async_copy16(uint16_t* lds, const uint16_t* g) {
  __builtin_amdgcn_global_load_lds(
      (const __attribute__((address_space(1))) uint32_t*)g,
      (__attribute__((address_space(3))) uint32_t*)lds, 16, 0, 0);
}

// ---- K1: tiled transpose+convert W (512x512) ----
__global__ __launch_bounds__(256) void conv_wt(const float* __restrict__ W,
                                               uint16_t* __restrict__ WT) {
  __shared__ float ts[64][65];
  int tid = threadIdx.x;
  int kt = (blockIdx.x >> 3) * 64, ct = (blockIdx.x & 7) * 64;
  #pragma unroll
  for (int it = 0; it < 4; ++it) {
    int idx = it * 256 + tid;
    int r = idx >> 4, q = idx & 15;
    float4v v = *(const float4v*)(W + (size_t)(kt + r) * 512 + ct + q * 4);
    ts[r][q * 4 + 0] = v.x; ts[r][q * 4 + 1] = v.y;
    ts[r][q * 4 + 2] = v.z; ts[r][q * 4 + 3] = v.w;
  }
  __syncthreads();
  #pragma unroll
  for (int it = 0; it < 4; ++it) {
    int idx = it * 256 + tid;
    int c = idx >> 4, q = idx & 15;
    ushort4v p;
    p.x = f2bf(ts[q * 4 + 0][c]); p.y = f2bf(ts[q * 4 + 1][c]);
    p.z = f2bf(ts[q * 4 + 2][c]); p.w = f2bf(ts[q * 4 + 3][c]);
    *(ushort4v*)(WT + (size_t)(ct + c) * 512 + kt + q * 4) = p;
  }
}

// ---- K2: Wh GEMM -> WhT[c][i] bf16, fused raw scores + exp factors ----
__global__ __launch_bounds__(512) void wh_gemm(const float* __restrict__ h,
                                               const uint16_t* __restrict__ WT,
                                               const float* __restrict__ bW,
                                               const float* __restrict__ a1,
                                               const float* __restrict__ a2,
                                               uint16_t* __restrict__ WhT,
                                               float* __restrict__ s1g,
                                               float* __restrict__ eb1g,
                                               float* __restrict__ eb2g) {
  __shared__ __align__(16) uint16_t At[32 * 32];
  __shared__ __align__(16) uint16_t Bt[512 * 32];
  __shared__ float s1loc[32], s2loc[32];
  int tid = threadIdx.x;
  int wave = tid >> 6, lane = tid & 63;
  int l15 = lane & 15, quad = lane >> 4;
  int i0 = blockIdx.x * 32;
  if (tid < 32) { s1loc[tid] = 0.f; s2loc[tid] = 0.f; }
  f32x4 acc[2][4] = {};
  for (int k0 = 0; k0 < 512; k0 += 32) {
    if (tid < 256) {
      int r = tid >> 3, ks = (tid & 7) * 4;
      float4v hv = *(const float4v*)(h + (size_t)(i0 + r) * 512 + k0 + ks);
      ushort4v p;
      p.x = f2bf(hv.x); p.y = f2bf(hv.y); p.z = f2bf(hv.z); p.w = f2bf(hv.w);
      *(ushort4v*)&At[r * 32 + ks] = p;
    }
    #pragma unroll
    for (int rr = 0; rr < 4; ++rr) {
      int idx = rr * 512 + tid;
      int c = idx >> 2, q = idx & 3;
      async_copy16(&Bt[idx * 8], WT + c * 512 + k0 + q * 8);
    }
    __syncthreads();
    short8 a0 = *(const short8*)&At[l15 * 32 + quad * 8];
    short8 a1f = *(const short8*)&At[(l15 + 16) * 32 + quad * 8];
    #pragma unroll
    for (int nt = 0; nt < 4; ++nt) {
      int c = wave * 64 + nt * 16 + l15;
      short8 b = *(const short8*)&Bt[c * 32 + quad * 8];
      acc[0][nt] = __builtin_amdgcn_mfma_f32_16x16x32_bf16(a0, b, acc[0][nt], 0, 0, 0);
      acc[1][nt] = __builtin_amdgcn_mfma_f32_16x16x32_bf16(a1f, b, acc[1][nt], 0, 0, 0);
    }
    __syncthreads();
  }
  // epilogue: bias, write WhT, per-row score partials
  #pragma unroll
  for (int mt = 0; mt < 2; ++mt) {
    int ib = i0 + mt * 16 + quad * 4;
    float r1[4] = {0.f, 0.f, 0.f, 0.f};
    float r2[4] = {0.f, 0.f, 0.f, 0.f};
    #pragma unroll
    for (int nt = 0; nt < 4; ++nt) {
      int c = wave * 64 + nt * 16 + l15;
      float bias = bW[c];
      float a1c = a1[c], a2c = a2[c];
      float v0 = acc[mt][nt].x + bias;
      float v1 = acc[mt][nt].y + bias;
      float v2 = acc[mt][nt].z + bias;
      float v3 = acc[mt][nt].w + bias;
      ushort4v p;
      p.x = f2bf(v0); p.y = f2bf(v1); p.z = f2bf(v2); p.w = f2bf(v3);
      *(ushort4v*)&WhT[(size_t)c * 8192 + ib] = p;
      r1[0] = fmaf(v0, a1c, r1[0]); r1[1] = fmaf(v1, a1c, r1[1]);
      r1[2] = fmaf(v2, a1c, r1[2]); r1[3] = fmaf(v3, a1c, r1[3]);
      r2[0] = fmaf(v0, a2c, r2[0]); r2[1] = fmaf(v1, a2c, r2[1]);
      r2[2] = fmaf(v2, a2c, r2[2]); r2[3] = fmaf(v3, a2c, r2[3]);
    }
    #pragma unroll
    for (int v = 0; v < 4; ++v) {
      int row = mt * 16 + quad * 4 + v;
      atomicAdd(&s1loc[row], r1[v]);
      atomicAdd(&s2loc[row], r2[v]);
    }
  }
  __syncthreads();
  if (tid < 32) {
    s1g[i0 + tid] = s1loc[tid];
    float v2 = s2loc[tid];
    eb1g[i0 + tid] = __expf(v2);
    eb2g[i0 + tid] = __expf(0.2f * v2);
  }
}

// score: w = adj>0 ? max(A1*eb1_j, A2*eb2_j) : 0   (== adj?exp(lrelu(t)):0)
#define SCORE(aval, e1, e2, A1v, A2v, rs, dst)                       \
  { float m_ = fmaxf((A1v) * (e1), (A2v) * (e2));                    \
    m_ = ((aval) > 0) ? m_ : 0.f;                                    \
    (rs) += m_; (dst) = m_; }

// ---- K3: fused attention: out = (w @ WhT^T) * dinv, w computed on the fly.
// 64x128 tile, BK=128, 512 thr = 8 waves as (rg 2 x cg 2 x kg 2):
//   wave -> kg = w&1 (K half), rg = (w>>1)&1 (32-row group), cg = w>>2
//   (64-col group). Per wave per iter: 4 A-reads + 8 B-reads + 16 MFMA.
// Block map: rb = blockIdx&127, cb = blockIdx>>7 -> the 4 blocks sharing an
// adj row-stripe are 128 apart == same XCD -> adj HBM-fetched once.
__global__ __launch_bounds__(512, 4) void fused_attn(const int* __restrict__ adj,
                                                     const float* __restrict__ s1,
                                                     const float* __restrict__ b1,
                                                     const float* __restrict__ b2,
                                                     const float* __restrict__ eb1,
                                                     const float* __restrict__ eb2,
                                                     const uint16_t* __restrict__ WhT,
                                                     float* __restrict__ out) {
  __shared__ __align__(16) uint16_t At[64 * 128];    // 16 KB, XOR-16 swizzled
  __shared__ __align__(16) uint16_t Bt[128 * 128];   // 32 KB, XOR-16 swizzled
  __shared__ float sdv[64];
  int tid = threadIdx.x;
  int wave = tid >> 6, lane = tid & 63;
  int l15 = lane & 15, quad = lane >> 4;
  int kg = wave & 1, rg = (wave >> 1) & 1, cg = wave >> 2;
  int rb = blockIdx.x & 127, cb = blockIdx.x >> 7;
  int i0 = rb * 64, c0 = cb * 128;
  int r0 = tid >> 4, pp = tid & 15;           // r0 in [0,32), chunk slot pp
  int sc = pp ^ (r0 & 15);                    // source chunk (involution)
  const int* arow0 = adj + (size_t)(i0 + r0) * NN + sc * 8;
  const int* arow1 = arow0 + (size_t)32 * NN;
  float bias = b1[0] + b2[0];
  float base0 = s1[i0 + r0] + bias;
  float base1 = s1[i0 + r0 + 32] + bias;
  float A10 = __expf(base0), A20 = __expf(0.2f * base0);
  float A11 = __expf(base1), A21 = __expf(0.2f * base1);
  float rsum0 = 0.f, rsum1 = 0.f;
  uint16_t* at0 = &At[(r0 * 16 + pp) * 8];
  uint16_t* at1 = &At[((r0 + 32) * 16 + pp) * 8];
  f32x4 acc[2][4] = {};
  for (int j0 = 0; j0 < NN; j0 += 128) {
    // A-side inputs first (oldest in vmcnt queue)
    int4 a00 = *(const int4*)(arow0 + j0);
    int4 a01 = *(const int4*)(arow0 + j0 + 4);
    int4 a10 = *(const int4*)(arow1 + j0);
    int4 a11 = *(const int4*)(arow1 + j0 + 4);
    float4v e1v0 = *(const float4v*)(eb1 + j0 + sc * 8);
    float4v e1v1 = *(const float4v*)(eb1 + j0 + sc * 8 + 4);
    float4v e2v0 = *(const float4v*)(eb2 + j0 + sc * 8);
    float4v e2v1 = *(const float4v*)(eb2 + j0 + sc * 8 + 4);
    // B: 128 rows x 128 j = 32 KB = 2048 x 16B chunks, 4/thread (async DMA)
    #pragma unroll
    for (int it = 0; it < 4; ++it) {
      int idx = it * 512 + tid;
      int r = idx >> 4, q = idx & 15;
      int bsc = q ^ (r & 15);
      async_copy16(&Bt[idx * 8], WhT + (size_t)(c0 + r) * NN + j0 + bsc * 8);
    }
    // scores: no transcendentals (factored exp), pack via cvt_pk
    float t0[8], t1[8];
    SCORE(a00.x, e1v0.x, e2v0.x, A10, A20, rsum0, t0[0]);
    SCORE(a00.y, e1v0.y, e2v0.y, A10, A20, rsum0, t0[1]);
    SCORE(a00.z, e1v0.z, e2v0.z, A10, A20, rsum0, t0[2]);
    SCORE(a00.w, e1v0.w, e2v0.w, A10, A20, rsum0, t0[3]);
    SCORE(a01.x, e1v1.x, e2v1.x, A10, A20, rsum0, t0[4]);
    SCORE(a01.y, e1v1.y, e2v1.y, A10, A20, rsum0, t0[5]);
    SCORE(a01.z, e1v1.z, e2v1.z, A10, A20, rsum0, t0[6]);
    SCORE(a01.w, e1v1.w, e2v1.w, A10, A20, rsum0, t0[7]);
    SCORE(a10.x, e1v0.x, e2v0.x, A11, A21, rsum1, t1[0]);
    SCORE(a10.y, e1v0.y, e2v0.y, A11, A21, rsum1, t1[1]);
    SCORE(a10.z, e1v0.z, e2v0.z, A11, A21, rsum1, t1[2]);
    SCORE(a10.w, e1v0.w, e2v0.w, A11, A21, rsum1, t1[3]);
    SCORE(a11.x, e1v1.x, e2v1.x, A11, A21, rsum1, t1[4]);
    SCORE(a11.y, e1v1.y, e2v1.y, A11, A21, rsum1, t1[5]);
    SCORE(a11.z, e1v1.z, e2v1.z, A11, A21, rsum1, t1[6]);
    SCORE(a11.w, e1v1.w, e2v1.w, A11, A21, rsum1, t1[7]);
    ushort8 w0, w1;
    uint32_t* pw0 = (uint32_t*)&w0;
    uint32_t* pw1 = (uint32_t*)&w1;
    pw0[0] = pk2bf(t0[0], t0[1]); pw0[1] = pk2bf(t0[2], t0[3]);
    pw0[2] = pk2bf(t0[4], t0[5]); pw0[3] = pk2bf(t0[6], t0[7]);
    pw1[0] = pk2bf(t1[0], t1[1]); pw1[1] = pk2bf(t1[2], t1[3]);
    pw1[2] = pk2bf(t1[4], t1[5]); pw1[3] = pk2bf(t1[6], t1[7]);
    *(ushort8*)at0 = w0;
    *(ushort8*)at1 = w1;
    __syncthreads();
    // MFMA phase: split-K — wave covers k in [kg*64, kg*64+64)
    #pragma unroll
    for (int kc = 0; kc < 2; ++kc) {
      int ch = kg * 8 + kc * 4 + quad;
      int ar0 = rg * 32 + l15, ar1 = ar0 + 16;
      short8 a0 = *(const short8*)&At[ar0 * 128 + ((ch ^ (ar0 & 15)) * 8)];
      short8 a1f = *(const short8*)&At[ar1 * 128 + ((ch ^ (ar1 & 15)) * 8)];
      #pragma unroll
      for (int ct = 0; ct < 4; ++ct) {
        int br = cg * 64 + ct * 16 + l15;
        short8 b = *(const short8*)&Bt[br * 128 + ((ch ^ (br & 15)) * 8)];
        acc[0][ct] = __builtin_amdgcn_mfma_f32_16x16x32_bf16(a0, b, acc[0][ct], 0, 0, 0);
        acc[1][ct] = __builtin_amdgcn_mfma_f32_16x16x32_bf16(a1f, b, acc[1][ct], 0, 0, 0);
      }
    }
    __syncthreads();
  }
  // dinv: reduce the 16 chunk-partials of each row (16 consecutive lanes)
  #pragma unroll
  for (int o = 1; o < 16; o <<= 1) {
    rsum0 += __shfl_xor(rsum0, o);
    rsum1 += __shfl_xor(rsum1, o);
  }
  if (pp == 0) {
    sdv[r0] = 1.0f / rsum0;
    sdv[r0 + 32] = 1.0f / rsum1;
  }
  // split-K reduction: kg=1 waves dump acc into Bt, kg=0 add + scale + store
  float* red = (float*)Bt;
  int pid = rg * 2 + cg;
  if (kg == 1) {
    #pragma unroll
    for (int rt = 0; rt < 2; ++rt)
      #pragma unroll
      for (int ct = 0; ct < 4; ++ct)
        #pragma unroll
        for (int v = 0; v < 4; ++v)
          red[pid * 2048 + ((rt * 4 + ct) * 4 + v) * 64 + lane] = acc[rt][ct][v];
  }
  __syncthreads();
  if (kg == 0) {
    #pragma unroll
    for (int rt = 0; rt < 2; ++rt) {
      #pragma unroll
      for (int v = 0; v < 4; ++v) {
        int rloc = rg * 32 + rt * 16 + quad * 4 + v;
        float dv = sdv[rloc];
        #pragma unroll
        for (int ct = 0; ct < 4; ++ct) {
          float s = acc[rt][ct][v] + red[pid * 2048 + ((rt * 4 + ct) * 4 + v) * 64 + lane];
          out[(size_t)(i0 + rloc) * DD + c0 + cg * 64 + ct * 16 + l15] = s * dv;
        }
      }
    }
  }
}

extern "C" void kernel_launch(void* const* d_in, const int* in_sizes, int n_in,
                              void* d_out, int out_size, void* d_ws, size_t ws_size,
                              hipStream_t stream) {
  const float* h   = (const float*)d_in[0];
  const int*   adj = (const int*)d_in[1];
  const float* W   = (const float*)d_in[2];
  const float* bW  = (const float*)d_in[3];
  const float* a1  = (const float*)d_in[4];
  const float* b1  = (const float*)d_in[5];
  const float* a2  = (const float*)d_in[6];
  const float* b2  = (const float*)d_in[7];
  float* out = (float*)d_out;
  char* ws = (char*)d_ws;

  uint16_t* WhT = (uint16_t*)(ws);                 // 8388608
  uint16_t* WT  = (uint16_t*)(ws + 8388608);       // 524288
  float* s1     = (float*)(ws + 8912896);          // 32768
  float* eb1    = (float*)(ws + 8945664);          // 32768
  float* eb2    = (float*)(ws + 8978432);          // 32768

  conv_wt<<<64, 256, 0, stream>>>(W, WT);
  wh_gemm<<<256, 512, 0, stream>>>(h, WT, bW, a1, a2, WhT, s1, eb1, eb2);
  fused_attn<<<512, 512, 0, stream>>>(adj, s1, b1, b2, eb1, eb2, WhT, out);
}